// Round 2
// baseline (1454.995 us; speedup 1.0000x reference)
//
#include <hip/hip_runtime.h>
#include <hip/hip_bf16.h>

typedef unsigned short u16;
typedef unsigned int u32;
typedef __attribute__((ext_vector_type(8))) short short8;
typedef __attribute__((ext_vector_type(4))) float float4v;

#define DEV __device__ __forceinline__

// B=2, N=2048, K=32, H=128, NODE_IN=64, EDGE_IN=48, DEPTH=3
constexpr int NN = 2048;
constexpr int BN = 4096;      // B*N
constexpr int NEDGE = 131072; // B*N*K
constexpr float SCALE_INV = 1.0f / 30.0f;
constexpr float EPS = 1e-6f;

DEV u16 f2bf(float f) {
    u32 u = __float_as_uint(f);
    u32 r = (u + 0x7fffu + ((u >> 16) & 1u)) >> 16;
    return (u16)r;
}
DEV float bf2f(u16 v) { return __uint_as_float(((u32)v) << 16); }

// block-wide sum over 128 threads (2 waves); all threads get result
DEV float blockSum128(float v, float* s2) {
    #pragma unroll
    for (int o = 32; o > 0; o >>= 1) v += __shfl_xor(v, o, 64);
    int t = threadIdx.x;
    if ((t & 63) == 0) s2[t >> 6] = v;
    __syncthreads();
    float r = s2[0] + s2[1];
    __syncthreads();
    return r;
}

// ---------------- h_v = norm(V @ Wv_w + Wv_b) : one node per block ----------
__global__ void k_node_embed(const float* __restrict__ V, const float* __restrict__ Ww,
                             const float* __restrict__ Wb, const float* __restrict__ Wg,
                             const float* __restrict__ Wb2, float* __restrict__ hout) {
    __shared__ float sV[64];
    __shared__ float s2[2];
    int r = blockIdx.x, c = threadIdx.x;
    if (c < 64) sV[c] = V[r * 64 + c];
    __syncthreads();
    float a = Wb[c];
    #pragma unroll 8
    for (int k = 0; k < 64; k++) a += sV[k] * Ww[k * 128 + c];
    float mu = blockSum128(a, s2) * (1.0f / 128.0f);
    float d = a - mu;
    float var = blockSum128(d * d, s2) * (1.0f / 127.0f);
    hout[r * 128 + c] = Wg[c] * d / (sqrtf(var) + EPS) + Wb2[c];
}

// ---------------- h_e = norm(E @ We_w + We_b) : 8 edge-rows per block -------
// output stored as bf16 (it only feeds the MFMA A-operand path)
__global__ void k_edge_embed(const float* __restrict__ E, const float* __restrict__ Ww,
                             const float* __restrict__ Wb, const float* __restrict__ Wg,
                             const float* __restrict__ Wb2, u16* __restrict__ he) {
    __shared__ float sE[8][48];
    __shared__ float s2[2];
    int rb = blockIdx.x * 8, t = threadIdx.x;
    for (int idx = t; idx < 384; idx += 128) {
        int r = idx / 48, c = idx - r * 48;
        sE[r][c] = E[(size_t)rb * 48 + idx];
    }
    __syncthreads();
    float acc[8];
    float bb = Wb[t];
    #pragma unroll
    for (int r = 0; r < 8; r++) acc[r] = bb;
    for (int k = 0; k < 48; k++) {
        float w = Ww[k * 128 + t];
        #pragma unroll
        for (int r = 0; r < 8; r++) acc[r] += sE[r][k] * w;
    }
    float g = Wg[t], b2 = Wb2[t];
    #pragma unroll
    for (int r = 0; r < 8; r++) {
        float mu = blockSum128(acc[r], s2) * (1.0f / 128.0f);
        float d = acc[r] - mu;
        float var = blockSum128(d * d, s2) * (1.0f / 127.0f);
        he[(size_t)(rb + r) * 128 + t] = f2bf(g * d / (sqrtf(var) + EPS) + b2);
    }
}

// ------- pack W1d (Lw1 rows 384..511) and Lw2 into MFMA B-fragment order ----
// frag element: B[k][n], n = 16*tt + (lane&15), k = 32*s + (lane>>4)*8 + j
__global__ void k_pack(const float* __restrict__ Lw1, const float* __restrict__ Lw2,
                       u16* __restrict__ pack) {
    int lm = blockIdx.x, l = lm >> 1, mat = lm & 1;
    const float* src = (mat == 0) ? (Lw1 + ((size_t)l * 512 + 384) * 128)
                                  : (Lw2 + (size_t)l * 128 * 128);
    u16* dst = pack + (size_t)lm * 16384;
    int t = threadIdx.x;
    for (int i = 0; i < 64; i++) {
        int idx = t * 64 + i;
        int j = idx & 7, lane = (idx >> 3) & 63, s = (idx >> 9) & 3, tt = idx >> 11;
        int k = s * 32 + (lane >> 4) * 8 + j;
        int n = tt * 16 + (lane & 15);
        dst[idx] = f2bf(src[k * 128 + n]);
    }
}

// ---------- per-layer node-level pre: P = h@W1a + b1 ; G = h@W1b + hS@W1c ---
__global__ void k_layer_pre(const float* __restrict__ h, const float* __restrict__ hS,
                            const float* __restrict__ Lw1, const float* __restrict__ Lb1,
                            int l, float* __restrict__ P, float* __restrict__ G) {
    __shared__ float sh[8][128];
    __shared__ float ss[8][128];
    int nb = blockIdx.x * 8, t = threadIdx.x;
    #pragma unroll
    for (int i = 0; i < 8; i++) {
        sh[i][t] = h[(size_t)(nb + i) * 128 + t];
        ss[i][t] = hS[(size_t)(nb + i) * 128 + t];
    }
    __syncthreads();
    float p[8], q[8];
    float b1 = Lb1[l * 128 + t];
    #pragma unroll
    for (int i = 0; i < 8; i++) { p[i] = b1; q[i] = 0.f; }
    const float* Wbase = Lw1 + (size_t)l * 512 * 128;
    for (int k = 0; k < 128; k++) {
        float wa = Wbase[k * 128 + t];
        float wb = Wbase[(128 + k) * 128 + t];
        float wc = Wbase[(256 + k) * 128 + t];
        #pragma unroll
        for (int i = 0; i < 8; i++) {
            p[i] += sh[i][k] * wa;
            q[i] += sh[i][k] * wb + ss[i][k] * wc;
        }
    }
    #pragma unroll
    for (int i = 0; i < 8; i++) {
        P[(size_t)(nb + i) * 128 + t] = p[i];
        G[(size_t)(nb + i) * 128 + t] = q[i];
    }
}

// ---------- per-layer edge MLP: MFMA. 4 nodes (128 edge-rows) per block -----
// GEMM1: m1 = relu(he@W1d + P[i] + G[j]) ; GEMM2: m2 = relu(m1@W2 + b2)
// Macc[i][:] = sum_k vmask * m2
__global__ __launch_bounds__(256, 2) void k_edge_mlp(
    const u16* __restrict__ he, const float* __restrict__ P, const float* __restrict__ G,
    const int* __restrict__ Eidx, const float* __restrict__ maskp,
    const u16* __restrict__ pack, const float* __restrict__ Lb2, int l,
    float* __restrict__ Macc) {
    __shared__ __align__(16) u16 sA[128 * 136];  // A tiles (he, then m1), pad 8 shorts
    __shared__ int sJ[128];
    __shared__ float sVm[128];
    __shared__ float sP[4 * 128];
    int nb = blockIdx.x * 4;  // global node row base
    int t = threadIdx.x;

    if (t < 128) {
        int gr = nb + (t >> 5);
        int j = Eidx[nb * 32 + t];
        int jg = (gr >> 11) * NN + j;  // add batch offset
        sJ[t] = jg;
        sVm[t] = maskp[jg];
    }
    sP[t] = P[(size_t)nb * 128 + t];
    sP[t + 256] = P[(size_t)nb * 128 + 256 + t];
    {   // stage he rows (contiguous 32KB) into padded LDS
        const uint4* src = (const uint4*)(he + (size_t)nb * 32 * 128);
        #pragma unroll
        for (int i = 0; i < 8; i++) {
            int idx = i * 256 + t;
            int row = idx >> 4, col = idx & 15;
            *(uint4*)(&sA[row * 136 + col * 8]) = src[idx];
        }
    }
    __syncthreads();

    int w = t >> 6, lane = t & 63, q = lane >> 4, c16 = lane & 15;

    short8 Bf[2][4];
    const short8* pk1 = (const short8*)(pack + (size_t)(l * 2) * 16384);
    #pragma unroll
    for (int tn = 0; tn < 2; tn++)
        #pragma unroll
        for (int s = 0; s < 4; s++)
            Bf[tn][s] = pk1[((2 * w + tn) * 4 + s) * 64 + lane];

    float4v acc[8][2];
    #pragma unroll
    for (int tm = 0; tm < 8; tm++)
        #pragma unroll
        for (int tn = 0; tn < 2; tn++) acc[tm][tn] = (float4v){0.f, 0.f, 0.f, 0.f};

    #pragma unroll
    for (int tm = 0; tm < 8; tm++) {
        short8 a[4];
        #pragma unroll
        for (int s = 0; s < 4; s++)
            a[s] = *(const short8*)(&sA[(tm * 16 + c16) * 136 + s * 32 + q * 8]);
        #pragma unroll
        for (int s = 0; s < 4; s++) {
            acc[tm][0] = __builtin_amdgcn_mfma_f32_16x16x32_bf16(a[s], Bf[0][s], acc[tm][0], 0, 0, 0);
            acc[tm][1] = __builtin_amdgcn_mfma_f32_16x16x32_bf16(a[s], Bf[1][s], acc[tm][1], 0, 0, 0);
        }
    }
    __syncthreads();  // all waves done reading he from sA

    // epilogue1: + P[i] + G[j], relu, write m1 (bf16) back into sA
    #pragma unroll
    for (int tm = 0; tm < 8; tm++) {
        #pragma unroll
        for (int tn = 0; tn < 2; tn++) {
            int n = (2 * w + tn) * 16 + c16;
            #pragma unroll
            for (int r = 0; r < 4; r++) {
                int m = tm * 16 + q * 4 + r;
                int g = m >> 5;
                float v = acc[tm][tn][r] + sP[g * 128 + n] + G[(size_t)sJ[m] * 128 + n];
                v = v > 0.f ? v : 0.f;
                sA[m * 136 + n] = f2bf(v);
            }
        }
    }
    __syncthreads();

    // GEMM2
    const short8* pk2 = (const short8*)(pack + (size_t)(l * 2 + 1) * 16384);
    #pragma unroll
    for (int tn = 0; tn < 2; tn++)
        #pragma unroll
        for (int s = 0; s < 4; s++)
            Bf[tn][s] = pk2[((2 * w + tn) * 4 + s) * 64 + lane];
    #pragma unroll
    for (int tm = 0; tm < 8; tm++)
        #pragma unroll
        for (int tn = 0; tn < 2; tn++) acc[tm][tn] = (float4v){0.f, 0.f, 0.f, 0.f};
    #pragma unroll
    for (int tm = 0; tm < 8; tm++) {
        short8 a[4];
        #pragma unroll
        for (int s = 0; s < 4; s++)
            a[s] = *(const short8*)(&sA[(tm * 16 + c16) * 136 + s * 32 + q * 8]);
        #pragma unroll
        for (int s = 0; s < 4; s++) {
            acc[tm][0] = __builtin_amdgcn_mfma_f32_16x16x32_bf16(a[s], Bf[0][s], acc[tm][0], 0, 0, 0);
            acc[tm][1] = __builtin_amdgcn_mfma_f32_16x16x32_bf16(a[s], Bf[1][s], acc[tm][1], 0, 0, 0);
        }
    }

    // epilogue2: +b2, relu, vmask-weighted sum over the 32 edges of each node
    float b2v0 = Lb2[l * 128 + (2 * w) * 16 + c16];
    float b2v1 = Lb2[l * 128 + (2 * w + 1) * 16 + c16];
    #pragma unroll
    for (int g = 0; g < 4; g++) {
        float p0 = 0.f, p1 = 0.f;
        #pragma unroll
        for (int half = 0; half < 2; half++) {
            int tm = 2 * g + half;
            #pragma unroll
            for (int r = 0; r < 4; r++) {
                int m = tm * 16 + q * 4 + r;
                float vm = sVm[m];
                float x0 = acc[tm][0][r] + b2v0; x0 = x0 > 0.f ? x0 : 0.f;
                float x1 = acc[tm][1][r] + b2v1; x1 = x1 > 0.f ? x1 : 0.f;
                p0 += vm * x0;
                p1 += vm * x1;
            }
        }
        p0 += __shfl_xor(p0, 16, 64); p0 += __shfl_xor(p0, 32, 64);
        p1 += __shfl_xor(p1, 16, 64); p1 += __shfl_xor(p1, 32, 64);
        if (lane < 32) {
            float val = (lane < 16) ? p0 : p1;
            int col = 32 * w + (lane & 31);
            Macc[(size_t)(nb + g) * 128 + col] = val;
        }
    }
}

// ---- per-layer node-level post: dh=(Macc@W3+msum*b3)/30; h=norm(h+dh)*mask -
__global__ void k_layer_post(const float* __restrict__ Macc, const int* __restrict__ Eidx,
                             const float* __restrict__ maskp, const float* __restrict__ Lw3,
                             const float* __restrict__ Lb3, const float* __restrict__ Lng,
                             const float* __restrict__ Lnb, int l, float* __restrict__ h,
                             float* __restrict__ outp, int last) {
    __shared__ float sm[8][128];
    __shared__ float s2[2];
    __shared__ float smsum[8];
    int nb = blockIdx.x * 8, t = threadIdx.x;
    #pragma unroll
    for (int i = 0; i < 8; i++) sm[i][t] = Macc[(size_t)(nb + i) * 128 + t];
    if (t < 8) smsum[t] = 0.f;
    __syncthreads();
    for (int e = t; e < 256; e += 128) {
        int i = e >> 5;
        int gr = nb + i;
        int j = Eidx[nb * 32 + e];
        int jg = (gr >> 11) * NN + j;
        atomicAdd(&smsum[i], maskp[jg]);
    }
    __syncthreads();
    float d[8];
    #pragma unroll
    for (int i = 0; i < 8; i++) d[i] = 0.f;
    const float* W3 = Lw3 + (size_t)l * 128 * 128;
    for (int k = 0; k < 128; k++) {
        float w = W3[k * 128 + t];
        #pragma unroll
        for (int i = 0; i < 8; i++) d[i] += sm[i][k] * w;
    }
    float b3 = Lb3[l * 128 + t];
    float g = Lng[l * 128 + t];
    float bn = Lnb[l * 128 + t];
    for (int i = 0; i < 8; i++) {
        int gr = nb + i;
        float x = h[(size_t)gr * 128 + t] + (d[i] + smsum[i] * b3) * SCALE_INV;
        float mu = blockSum128(x, s2) * (1.0f / 128.0f);
        float dd = x - mu;
        float var = blockSum128(dd * dd, s2) * (1.0f / 127.0f);
        float mval = maskp[gr];
        float out = (g * dd / (sqrtf(var) + EPS) + bn) * mval;
        h[(size_t)gr * 128 + t] = out;
        if (last) outp[(size_t)gr * 128 + t] = out;
    }
}

extern "C" void kernel_launch(void* const* d_in, const int* in_sizes, int n_in,
                              void* d_out, int out_size, void* d_ws, size_t ws_size,
                              hipStream_t stream) {
    const float* V     = (const float*)d_in[0];
    const float* E     = (const float*)d_in[1];
    const float* hS    = (const float*)d_in[2];
    const int*   Eidx  = (const int*)d_in[3];
    const float* maskp = (const float*)d_in[4];
    const float* Wv_w  = (const float*)d_in[5];
    const float* Wv_b  = (const float*)d_in[6];
    const float* Wv_g  = (const float*)d_in[7];
    const float* Wv_b2 = (const float*)d_in[8];
    const float* We_w  = (const float*)d_in[9];
    const float* We_b  = (const float*)d_in[10];
    const float* We_g  = (const float*)d_in[11];
    const float* We_b2 = (const float*)d_in[12];
    const float* Lw1   = (const float*)d_in[13];
    const float* Lb1   = (const float*)d_in[14];
    const float* Lw2   = (const float*)d_in[15];
    const float* Lb2   = (const float*)d_in[16];
    const float* Lw3   = (const float*)d_in[17];
    const float* Lb3   = (const float*)d_in[18];
    const float* Ln_g  = (const float*)d_in[19];
    const float* Ln_b  = (const float*)d_in[20];

    char* ws = (char*)d_ws;
    float* h    = (float*)ws; ws += (size_t)BN * 128 * 4;
    float* P    = (float*)ws; ws += (size_t)BN * 128 * 4;
    float* G    = (float*)ws; ws += (size_t)BN * 128 * 4;
    float* Macc = (float*)ws; ws += (size_t)BN * 128 * 4;
    u16*   he   = (u16*)ws;   ws += (size_t)NEDGE * 128 * 2;
    u16*   pack = (u16*)ws;   ws += (size_t)6 * 16384 * 2;

    k_node_embed<<<BN, 128, 0, stream>>>(V, Wv_w, Wv_b, Wv_g, Wv_b2, h);
    k_edge_embed<<<NEDGE / 8, 128, 0, stream>>>(E, We_w, We_b, We_g, We_b2, he);
    k_pack<<<6, 256, 0, stream>>>(Lw1, Lw2, pack);
    for (int l = 0; l < 3; l++) {
        k_layer_pre<<<BN / 8, 128, 0, stream>>>(h, hS, Lw1, Lb1, l, P, G);
        k_edge_mlp<<<BN / 4, 256, 0, stream>>>(he, P, G, Eidx, maskp, pack, Lb2, l, Macc);
        k_layer_post<<<BN / 8, 128, 0, stream>>>(Macc, Eidx, maskp, Lw3, Lb3, Ln_g, Ln_b,
                                                 l, h, (float*)d_out, l == 2);
    }
}

// Round 3
// 384.597 us; speedup vs baseline: 3.7832x; 3.7832x over previous
//
#include <hip/hip_runtime.h>
#include <hip/hip_bf16.h>

typedef unsigned short u16;
typedef unsigned int u32;
typedef __attribute__((ext_vector_type(8))) short short8;
typedef __attribute__((ext_vector_type(4))) float float4v;

#define DEV __device__ __forceinline__

// B=2, N=2048, K=32, H=128, NODE_IN=64, EDGE_IN=48, DEPTH=3
constexpr int NN = 2048;
constexpr int BN = 4096;      // B*N
constexpr int NEDGE = 131072; // B*N*K
constexpr float SCALE_INV = 1.0f / 30.0f;
constexpr float EPS = 1e-6f;

DEV u16 f2bf(float f) {
    u32 u = __float_as_uint(f);
    u32 r = (u + 0x7fffu + ((u >> 16) & 1u)) >> 16;
    return (u16)r;
}

// block-wide sum over 128 threads (2 waves); all threads get result
// (only used with SCALAR operands — never array elements, to avoid scratch demotion)
DEV float blockSum128(float v, float* s2) {
    #pragma unroll
    for (int o = 32; o > 0; o >>= 1) v += __shfl_xor(v, o, 64);
    int t = threadIdx.x;
    if ((t & 63) == 0) s2[t >> 6] = v;
    __syncthreads();
    float r = s2[0] + s2[1];
    __syncthreads();
    return r;
}

// ---------------- h_v = norm(V @ Wv_w + Wv_b) : one node per block ----------
__global__ void k_node_embed(const float* __restrict__ V, const float* __restrict__ Ww,
                             const float* __restrict__ Wb, const float* __restrict__ Wg,
                             const float* __restrict__ Wb2, float* __restrict__ hout) {
    __shared__ float sV[64];
    __shared__ float s2[2];
    int r = blockIdx.x, c = threadIdx.x;
    if (c < 64) sV[c] = V[r * 64 + c];
    __syncthreads();
    float a = Wb[c];
    #pragma unroll 8
    for (int k = 0; k < 64; k++) a += sV[k] * Ww[k * 128 + c];
    float mu = blockSum128(a, s2) * (1.0f / 128.0f);
    float d = a - mu;
    float var = blockSum128(d * d, s2) * (1.0f / 127.0f);
    hout[r * 128 + c] = Wg[c] * d / (sqrtf(var) + EPS) + Wb2[c];
}

// ---------------- h_e = norm(E @ We_w + We_b) : thread-per-edge-row ---------
// Each thread owns one edge row: 128 accumulators in VGPRs (float4v[32], all
// compile-time indexed), weights via wave-uniform scalar loads, norm is a
// PRIVATE reduction (no barriers, no cross-lane). Output bf16.
__global__ __launch_bounds__(256) void k_edge_embed(
    const float* __restrict__ E, const float* __restrict__ Ww,
    const float* __restrict__ Wb, const float* __restrict__ Wg,
    const float* __restrict__ Wb2, u16* __restrict__ he) {
    __shared__ float sE[256 * 49];  // stride 49: 17t mod 32 bijective -> conflict-free
    int t = threadIdx.x;
    size_t rowbase = (size_t)blockIdx.x * 256;
    const float* src = E + rowbase * 48;
    for (int idx = t; idx < 256 * 48; idx += 256) {
        int r = idx / 48, c = idx - r * 48;
        sE[r * 49 + c] = src[idx];
    }
    __syncthreads();

    const float4v* Wb4 = (const float4v*)Wb;
    float4v acc[32];
    #pragma unroll
    for (int ci = 0; ci < 32; ci++) acc[ci] = Wb4[ci];  // uniform s_load

    const float* eRow = &sE[t * 49];
    #pragma unroll 2
    for (int k = 0; k < 48; k++) {
        float ek = eRow[k];
        const float4v* w4 = (const float4v*)(Ww + k * 128);  // uniform -> s_load
        #pragma unroll
        for (int ci = 0; ci < 32; ci++) acc[ci] += ek * w4[ci];
    }

    // private layernorm (ddof=1)
    float s = 0.f;
    #pragma unroll
    for (int ci = 0; ci < 32; ci++)
        s += acc[ci][0] + acc[ci][1] + acc[ci][2] + acc[ci][3];
    float mu = s * (1.0f / 128.0f);
    float vs = 0.f;
    #pragma unroll
    for (int ci = 0; ci < 32; ci++) {
        #pragma unroll
        for (int p = 0; p < 4; p++) { float dd = acc[ci][p] - mu; vs += dd * dd; }
    }
    float inv = 1.0f / (sqrtf(vs * (1.0f / 127.0f)) + EPS);

    uint4* dst4 = (uint4*)(he + (rowbase + t) * 128);
    #pragma unroll
    for (int cc = 0; cc < 16; cc++) {  // 8 bf16 per store
        u32 wbuf[4];
        #pragma unroll
        for (int p = 0; p < 4; p++) {
            int c0 = cc * 8 + p * 2;
            float o0 = Wg[c0] * (acc[c0 >> 2][c0 & 3] - mu) * inv + Wb2[c0];
            int c1 = c0 + 1;
            float o1 = Wg[c1] * (acc[c1 >> 2][c1 & 3] - mu) * inv + Wb2[c1];
            wbuf[p] = (u32)f2bf(o0) | ((u32)f2bf(o1) << 16);
        }
        dst4[cc] = make_uint4(wbuf[0], wbuf[1], wbuf[2], wbuf[3]);
    }
}

// ------- pack W1d (Lw1 rows 384..511) and Lw2 into MFMA B-fragment order ----
// frag element: B[k][n], n = 16*tt + (lane&15), k = 32*s + (lane>>4)*8 + j
__global__ void k_pack(const float* __restrict__ Lw1, const float* __restrict__ Lw2,
                       u16* __restrict__ pack) {
    int lm = blockIdx.x, l = lm >> 1, mat = lm & 1;
    const float* src = (mat == 0) ? (Lw1 + ((size_t)l * 512 + 384) * 128)
                                  : (Lw2 + (size_t)l * 128 * 128);
    u16* dst = pack + (size_t)lm * 16384;
    int t = threadIdx.x;
    for (int i = 0; i < 64; i++) {
        int idx = t * 64 + i;
        int j = idx & 7, lane = (idx >> 3) & 63, s = (idx >> 9) & 3, tt = idx >> 11;
        int k = s * 32 + (lane >> 4) * 8 + j;
        int n = tt * 16 + (lane & 15);
        dst[idx] = f2bf(src[k * 128 + n]);
    }
}

// ---------- per-layer node-level pre: P = h@W1a + b1 ; G = h@W1b + hS@W1c ---
__global__ void k_layer_pre(const float* __restrict__ h, const float* __restrict__ hS,
                            const float* __restrict__ Lw1, const float* __restrict__ Lb1,
                            int l, float* __restrict__ P, float* __restrict__ G) {
    __shared__ float sh[8][128];
    __shared__ float ss[8][128];
    int nb = blockIdx.x * 8, t = threadIdx.x;
    #pragma unroll
    for (int i = 0; i < 8; i++) {
        sh[i][t] = h[(size_t)(nb + i) * 128 + t];
        ss[i][t] = hS[(size_t)(nb + i) * 128 + t];
    }
    __syncthreads();
    float p[8], q[8];
    float b1 = Lb1[l * 128 + t];
    #pragma unroll
    for (int i = 0; i < 8; i++) { p[i] = b1; q[i] = 0.f; }
    const float* Wbase = Lw1 + (size_t)l * 512 * 128;
    for (int k = 0; k < 128; k++) {
        float wa = Wbase[k * 128 + t];
        float wb = Wbase[(128 + k) * 128 + t];
        float wc = Wbase[(256 + k) * 128 + t];
        #pragma unroll
        for (int i = 0; i < 8; i++) {
            p[i] += sh[i][k] * wa;
            q[i] += sh[i][k] * wb + ss[i][k] * wc;
        }
    }
    #pragma unroll
    for (int i = 0; i < 8; i++) {
        P[(size_t)(nb + i) * 128 + t] = p[i];
        G[(size_t)(nb + i) * 128 + t] = q[i];
    }
}

// ---------- per-layer edge MLP: MFMA. 4 nodes (128 edge-rows) per block -----
// GEMM1: m1 = relu(he@W1d + P[i] + G[j]) ; GEMM2: m2 = relu(m1@W2 + b2)
// Macc[i][:] = sum_k vmask * m2
__global__ __launch_bounds__(256, 2) void k_edge_mlp(
    const u16* __restrict__ he, const float* __restrict__ P, const float* __restrict__ G,
    const int* __restrict__ Eidx, const float* __restrict__ maskp,
    const u16* __restrict__ pack, const float* __restrict__ Lb2, int l,
    float* __restrict__ Macc) {
    __shared__ __align__(16) u16 sA[128 * 136];  // A tiles (he, then m1), pad 8 shorts
    __shared__ int sJ[128];
    __shared__ float sVm[128];
    __shared__ float sP[4 * 128];
    int nb = blockIdx.x * 4;  // global node row base
    int t = threadIdx.x;

    if (t < 128) {
        int gr = nb + (t >> 5);
        int j = Eidx[nb * 32 + t];
        int jg = (gr >> 11) * NN + j;  // add batch offset
        sJ[t] = jg;
        sVm[t] = maskp[jg];
    }
    sP[t] = P[(size_t)nb * 128 + t];
    sP[t + 256] = P[(size_t)nb * 128 + 256 + t];
    {   // stage he rows (contiguous 32KB) into padded LDS
        const uint4* src = (const uint4*)(he + (size_t)nb * 32 * 128);
        #pragma unroll
        for (int i = 0; i < 8; i++) {
            int idx = i * 256 + t;
            int row = idx >> 4, col = idx & 15;
            *(uint4*)(&sA[row * 136 + col * 8]) = src[idx];
        }
    }
    __syncthreads();

    int w = t >> 6, lane = t & 63, q = lane >> 4, c16 = lane & 15;

    short8 Bf[2][4];
    const short8* pk1 = (const short8*)(pack + (size_t)(l * 2) * 16384);
    #pragma unroll
    for (int tn = 0; tn < 2; tn++)
        #pragma unroll
        for (int s = 0; s < 4; s++)
            Bf[tn][s] = pk1[((2 * w + tn) * 4 + s) * 64 + lane];

    float4v acc[8][2];
    #pragma unroll
    for (int tm = 0; tm < 8; tm++)
        #pragma unroll
        for (int tn = 0; tn < 2; tn++) acc[tm][tn] = (float4v){0.f, 0.f, 0.f, 0.f};

    #pragma unroll
    for (int tm = 0; tm < 8; tm++) {
        short8 a[4];
        #pragma unroll
        for (int s = 0; s < 4; s++)
            a[s] = *(const short8*)(&sA[(tm * 16 + c16) * 136 + s * 32 + q * 8]);
        #pragma unroll
        for (int s = 0; s < 4; s++) {
            acc[tm][0] = __builtin_amdgcn_mfma_f32_16x16x32_bf16(a[s], Bf[0][s], acc[tm][0], 0, 0, 0);
            acc[tm][1] = __builtin_amdgcn_mfma_f32_16x16x32_bf16(a[s], Bf[1][s], acc[tm][1], 0, 0, 0);
        }
    }
    __syncthreads();  // all waves done reading he from sA

    // epilogue1: + P[i] + G[j], relu, write m1 (bf16) back into sA
    #pragma unroll
    for (int tm = 0; tm < 8; tm++) {
        #pragma unroll
        for (int tn = 0; tn < 2; tn++) {
            int n = (2 * w + tn) * 16 + c16;
            #pragma unroll
            for (int r = 0; r < 4; r++) {
                int m = tm * 16 + q * 4 + r;
                int g = m >> 5;
                float v = acc[tm][tn][r] + sP[g * 128 + n] + G[(size_t)sJ[m] * 128 + n];
                v = v > 0.f ? v : 0.f;
                sA[m * 136 + n] = f2bf(v);
            }
        }
    }
    __syncthreads();

    // GEMM2
    const short8* pk2 = (const short8*)(pack + (size_t)(l * 2 + 1) * 16384);
    #pragma unroll
    for (int tn = 0; tn < 2; tn++)
        #pragma unroll
        for (int s = 0; s < 4; s++)
            Bf[tn][s] = pk2[((2 * w + tn) * 4 + s) * 64 + lane];
    #pragma unroll
    for (int tm = 0; tm < 8; tm++)
        #pragma unroll
        for (int tn = 0; tn < 2; tn++) acc[tm][tn] = (float4v){0.f, 0.f, 0.f, 0.f};
    #pragma unroll
    for (int tm = 0; tm < 8; tm++) {
        short8 a[4];
        #pragma unroll
        for (int s = 0; s < 4; s++)
            a[s] = *(const short8*)(&sA[(tm * 16 + c16) * 136 + s * 32 + q * 8]);
        #pragma unroll
        for (int s = 0; s < 4; s++) {
            acc[tm][0] = __builtin_amdgcn_mfma_f32_16x16x32_bf16(a[s], Bf[0][s], acc[tm][0], 0, 0, 0);
            acc[tm][1] = __builtin_amdgcn_mfma_f32_16x16x32_bf16(a[s], Bf[1][s], acc[tm][1], 0, 0, 0);
        }
    }

    // epilogue2: +b2, relu, vmask-weighted sum over the 32 edges of each node
    float b2v0 = Lb2[l * 128 + (2 * w) * 16 + c16];
    float b2v1 = Lb2[l * 128 + (2 * w + 1) * 16 + c16];
    #pragma unroll
    for (int g = 0; g < 4; g++) {
        float p0 = 0.f, p1 = 0.f;
        #pragma unroll
        for (int half = 0; half < 2; half++) {
            int tm = 2 * g + half;
            #pragma unroll
            for (int r = 0; r < 4; r++) {
                int m = tm * 16 + q * 4 + r;
                float vm = sVm[m];
                float x0 = acc[tm][0][r] + b2v0; x0 = x0 > 0.f ? x0 : 0.f;
                float x1 = acc[tm][1][r] + b2v1; x1 = x1 > 0.f ? x1 : 0.f;
                p0 += vm * x0;
                p1 += vm * x1;
            }
        }
        p0 += __shfl_xor(p0, 16, 64); p0 += __shfl_xor(p0, 32, 64);
        p1 += __shfl_xor(p1, 16, 64); p1 += __shfl_xor(p1, 32, 64);
        if (lane < 32) {
            float val = (lane < 16) ? p0 : p1;
            int col = 32 * w + (lane & 31);
            Macc[(size_t)(nb + g) * 128 + col] = val;
        }
    }
}

// ---- per-layer node-level post: dh=(Macc@W3+msum*b3)/30; h=norm(h+dh)*mask -
// Batched barrier-free wave reductions; NO barrier inside any unrolled loop
// (prevents scratch demotion of d[]/x[]).
__global__ void k_layer_post(const float* __restrict__ Macc, const int* __restrict__ Eidx,
                             const float* __restrict__ maskp, const float* __restrict__ Lw3,
                             const float* __restrict__ Lb3, const float* __restrict__ Lng,
                             const float* __restrict__ Lnb, int l, float* __restrict__ h,
                             float* __restrict__ outp, int last) {
    __shared__ float sm[8][128];
    __shared__ float sred[2][8];
    __shared__ float smsum[8];
    int nb = blockIdx.x * 8, t = threadIdx.x;
    int wv = t >> 6, lane = t & 63;
    #pragma unroll
    for (int i = 0; i < 8; i++) sm[i][t] = Macc[(size_t)(nb + i) * 128 + t];
    if (t < 8) smsum[t] = 0.f;
    __syncthreads();
    for (int e = t; e < 256; e += 128) {
        int i = e >> 5;
        int gr = nb + i;
        int j = Eidx[nb * 32 + e];
        int jg = (gr >> 11) * NN + j;
        atomicAdd(&smsum[i], maskp[jg]);
    }
    __syncthreads();
    float d[8];
    #pragma unroll
    for (int i = 0; i < 8; i++) d[i] = 0.f;
    const float* W3 = Lw3 + (size_t)l * 128 * 128;
    for (int k = 0; k < 128; k++) {
        float w = W3[k * 128 + t];
        #pragma unroll
        for (int i = 0; i < 8; i++) d[i] += sm[i][k] * w;
    }
    float b3 = Lb3[l * 128 + t];
    float g = Lng[l * 128 + t];
    float bn = Lnb[l * 128 + t];
    float x[8];
    #pragma unroll
    for (int i = 0; i < 8; i++)
        x[i] = h[(size_t)(nb + i) * 128 + t] + (d[i] + smsum[i] * b3) * SCALE_INV;
    // batched mean (wave reduce, 1 barrier)
    #pragma unroll
    for (int i = 0; i < 8; i++) {
        float v = x[i];
        #pragma unroll
        for (int o = 32; o > 0; o >>= 1) v += __shfl_xor(v, o, 64);
        if (lane == 0) sred[wv][i] = v;
    }
    __syncthreads();
    float mu[8];
    #pragma unroll
    for (int i = 0; i < 8; i++) mu[i] = (sred[0][i] + sred[1][i]) * (1.0f / 128.0f);
    __syncthreads();
    // batched variance (wave reduce, 1 barrier)
    #pragma unroll
    for (int i = 0; i < 8; i++) {
        float dd = x[i] - mu[i];
        float v = dd * dd;
        #pragma unroll
        for (int o = 32; o > 0; o >>= 1) v += __shfl_xor(v, o, 64);
        if (lane == 0) sred[wv][i] = v;
    }
    __syncthreads();
    #pragma unroll
    for (int i = 0; i < 8; i++) {
        float var = (sred[0][i] + sred[1][i]) * (1.0f / 127.0f);
        int gr = nb + i;
        float mval = maskp[gr];
        float out = (g * (x[i] - mu[i]) / (sqrtf(var) + EPS) + bn) * mval;
        h[(size_t)gr * 128 + t] = out;
        if (last) outp[(size_t)gr * 128 + t] = out;
    }
}

extern "C" void kernel_launch(void* const* d_in, const int* in_sizes, int n_in,
                              void* d_out, int out_size, void* d_ws, size_t ws_size,
                              hipStream_t stream) {
    const float* V     = (const float*)d_in[0];
    const float* E     = (const float*)d_in[1];
    const float* hS    = (const float*)d_in[2];
    const int*   Eidx  = (const int*)d_in[3];
    const float* maskp = (const float*)d_in[4];
    const float* Wv_w  = (const float*)d_in[5];
    const float* Wv_b  = (const float*)d_in[6];
    const float* Wv_g  = (const float*)d_in[7];
    const float* Wv_b2 = (const float*)d_in[8];
    const float* We_w  = (const float*)d_in[9];
    const float* We_b  = (const float*)d_in[10];
    const float* We_g  = (const float*)d_in[11];
    const float* We_b2 = (const float*)d_in[12];
    const float* Lw1   = (const float*)d_in[13];
    const float* Lb1   = (const float*)d_in[14];
    const float* Lw2   = (const float*)d_in[15];
    const float* Lb2   = (const float*)d_in[16];
    const float* Lw3   = (const float*)d_in[17];
    const float* Lb3   = (const float*)d_in[18];
    const float* Ln_g  = (const float*)d_in[19];
    const float* Ln_b  = (const float*)d_in[20];

    char* ws = (char*)d_ws;
    float* h    = (float*)ws; ws += (size_t)BN * 128 * 4;
    float* P    = (float*)ws; ws += (size_t)BN * 128 * 4;
    float* G    = (float*)ws; ws += (size_t)BN * 128 * 4;
    float* Macc = (float*)ws; ws += (size_t)BN * 128 * 4;
    u16*   he   = (u16*)ws;   ws += (size_t)NEDGE * 128 * 2;
    u16*   pack = (u16*)ws;   ws += (size_t)6 * 16384 * 2;

    k_node_embed<<<BN, 128, 0, stream>>>(V, Wv_w, Wv_b, Wv_g, Wv_b2, h);
    k_edge_embed<<<NEDGE / 256, 256, 0, stream>>>(E, We_w, We_b, We_g, We_b2, he);
    k_pack<<<6, 256, 0, stream>>>(Lw1, Lw2, pack);
    for (int l = 0; l < 3; l++) {
        k_layer_pre<<<BN / 8, 128, 0, stream>>>(h, hS, Lw1, Lb1, l, P, G);
        k_edge_mlp<<<BN / 4, 256, 0, stream>>>(he, P, G, Eidx, maskp, pack, Lb2, l, Macc);
        k_layer_post<<<BN / 8, 128, 0, stream>>>(Macc, Eidx, maskp, Lw3, Lb3, Ln_g, Ln_b,
                                                 l, h, (float*)d_out, l == 2);
    }
}